// Round 1
// baseline (133.955 us; speedup 1.0000x reference)
//
#include <hip/hip_runtime.h>

#define NPTS 4096
#define ROWS_PER_WAVE 4
#define WAVES_PER_BLOCK 4
#define ROWS_PER_BLOCK (ROWS_PER_WAVE * WAVES_PER_BLOCK)

// Sorted-ascending top-4 insertion (all indices constant after inline -> registers)
__device__ __forceinline__ void ins4(float (&v)[4], int (&id)[4], float d, int j) {
    if (d < v[3]) {
        v[3] = d; id[3] = j;
        if (v[3] < v[2]) { float a = v[2]; v[2] = v[3]; v[3] = a; int b = id[2]; id[2] = id[3]; id[3] = b; }
        if (v[2] < v[1]) { float a = v[1]; v[1] = v[2]; v[2] = a; int b = id[1]; id[1] = id[2]; id[2] = b; }
        if (v[1] < v[0]) { float a = v[0]; v[0] = v[1]; v[1] = a; int b = id[0]; id[0] = id[1]; id[1] = b; }
    }
}

// xW = x @ W : [8192,128] @ [128,128], f32 vector ALU (no f32 MFMA on CDNA4).
// 8 rows/block, 32 threads/row, 4 outputs/thread via float4 W loads.
__global__ __launch_bounds__(256) void xw_gemm(const float* __restrict__ x,
                                               const float* __restrict__ W,
                                               float* __restrict__ xW) {
    int t = threadIdx.x;
    int rloc = t >> 5;            // 0..7
    int dq = (t & 31) << 2;       // 0,4,...,124
    size_t row = (size_t)blockIdx.x * 8 + rloc;
    const float* xr = x + row * 128;
    float4 acc = make_float4(0.f, 0.f, 0.f, 0.f);
#pragma unroll 8
    for (int c = 0; c < 128; ++c) {
        float xv = xr[c];
        float4 wv = *(const float4*)(W + c * 128 + dq);
        acc.x = fmaf(xv, wv.x, acc.x);
        acc.y = fmaf(xv, wv.y, acc.y);
        acc.z = fmaf(xv, wv.z, acc.z);
        acc.w = fmaf(xv, wv.w, acc.w);
    }
    *(float4*)(xW + row * 128 + dq) = acc;
}

// One wave handles 4 query rows; lanes scan strided j, sharing pos[j] loads
// across the 4 rows; butterfly-merge per-lane top4 -> global top4; epilogue
// gathers 4 rows of xW with normalized Gaussian weights.
__global__ __launch_bounds__(256) void topk_agg(const float* __restrict__ pos,
                                                const float* __restrict__ xW,
                                                const float* __restrict__ bias,
                                                float* __restrict__ out) {
    int lane = threadIdx.x & 63;
    int wave = threadIdx.x >> 6;
    int rowbase = blockIdx.x * ROWS_PER_BLOCK + wave * ROWS_PER_WAVE;  // 16 rows/block, never straddles batch
    int batch = rowbase >> 12;
    int ibase = rowbase & (NPTS - 1);
    const float* posb = pos + (size_t)batch * NPTS * 3;

    float v[ROWS_PER_WAVE][4];
    int   id[ROWS_PER_WAVE][4];
    float cx[ROWS_PER_WAVE], cy[ROWS_PER_WAVE], cz[ROWS_PER_WAVE];
#pragma unroll
    for (int k = 0; k < ROWS_PER_WAVE; ++k) {
        cx[k] = posb[(ibase + k) * 3 + 0];
        cy[k] = posb[(ibase + k) * 3 + 1];
        cz[k] = posb[(ibase + k) * 3 + 2];
#pragma unroll
        for (int r = 0; r < 4; ++r) { v[k][r] = 3.4e38f; id[k][r] = 0; }
    }

    for (int j = lane; j < NPTS; j += 64) {
        float px = posb[3 * j + 0];
        float py = posb[3 * j + 1];
        float pz = posb[3 * j + 2];
#pragma unroll
        for (int k = 0; k < ROWS_PER_WAVE; ++k) {
            float dx = cx[k] - px, dy = cy[k] - py, dz = cz[k] - pz;
            float d2 = fmaf(dx, dx, fmaf(dy, dy, dz * dz));
            ins4(v[k], id[k], d2, j);
        }
    }

    // Butterfly merge: after 6 xor steps every lane holds the global top-4.
#pragma unroll
    for (int k = 0; k < ROWS_PER_WAVE; ++k) {
        for (int off = 1; off < 64; off <<= 1) {
            float pv[4]; int pid[4];
#pragma unroll
            for (int r = 0; r < 4; ++r) {
                pv[r] = __shfl_xor(v[k][r], off);
                pid[r] = __shfl_xor(id[k][r], off);
            }
#pragma unroll
            for (int r = 0; r < 4; ++r) ins4(v[k], id[k], pv[r], pid[r]);
        }
    }

    // Epilogue: lane owns channels (2*lane, 2*lane+1)
    int c = lane << 1;
    float2 bb = *(const float2*)(bias + c);
    size_t bbase = ((size_t)batch * NPTS) << 7;
#pragma unroll
    for (int k = 0; k < ROWS_PER_WAVE; ++k) {
        float w0 = expf(-(v[k][0] + 1e-8f) * 0.5f);
        float w1 = expf(-(v[k][1] + 1e-8f) * 0.5f);
        float w2 = expf(-(v[k][2] + 1e-8f) * 0.5f);
        float w3 = expf(-(v[k][3] + 1e-8f) * 0.5f);
        float inv = 1.0f / (w0 + w1 + w2 + w3 + 1e-8f);
        w0 *= inv; w1 *= inv; w2 *= inv; w3 *= inv;
        float2 a0 = *(const float2*)(xW + bbase + ((size_t)id[k][0] << 7) + c);
        float2 a1 = *(const float2*)(xW + bbase + ((size_t)id[k][1] << 7) + c);
        float2 a2 = *(const float2*)(xW + bbase + ((size_t)id[k][2] << 7) + c);
        float2 a3 = *(const float2*)(xW + bbase + ((size_t)id[k][3] << 7) + c);
        float ox = bb.x + w0 * a0.x + w1 * a1.x + w2 * a2.x + w3 * a3.x;
        float oy = bb.y + w0 * a0.y + w1 * a1.y + w2 * a2.y + w3 * a3.y;
        *(float2*)(out + (((size_t)(rowbase + k)) << 7) + c) = make_float2(ox, oy);
    }
}

extern "C" void kernel_launch(void* const* d_in, const int* in_sizes, int n_in,
                              void* d_out, int out_size, void* d_ws, size_t ws_size,
                              hipStream_t stream) {
    const float* x    = (const float*)d_in[0];  // [2,4096,128]
    const float* pos  = (const float*)d_in[1];  // [2,4096,3]
    const float* W    = (const float*)d_in[2];  // [128,128]
    const float* bias = (const float*)d_in[3];  // [128]
    float* out = (float*)d_out;                 // [2,4096,128]
    float* xW  = (float*)d_ws;                  // 8192*128 f32 = 4 MB scratch

    xw_gemm<<<8192 / 8, 256, 0, stream>>>(x, W, xW);
    topk_agg<<<8192 / ROWS_PER_BLOCK, 256, 0, stream>>>(pos, xW, bias, out);
}

// Round 2
// 104.450 us; speedup vs baseline: 1.2825x; 1.2825x over previous
//
#include <hip/hip_runtime.h>
#include <hip/hip_bf16.h>

#define NPTS 4096
#define NROWS 8192   // B*N
#define DIM 128
#define RPW 2        // rows per wave in topk

typedef __attribute__((ext_vector_type(8))) short bf16x8;
typedef __attribute__((ext_vector_type(4))) float f32x4;

// ---------- prep: pos -> float4[8192], W -> W^T bf16 ----------
__global__ __launch_bounds__(256) void prep(const float* __restrict__ pos,
                                            const float* __restrict__ W,
                                            float4* __restrict__ pos4,
                                            __hip_bfloat16* __restrict__ Wt) {
    int t = blockIdx.x * 256 + threadIdx.x;
    if (t < NROWS) {
        const float* p = pos + (size_t)t * 3;
        pos4[t] = make_float4(p[0], p[1], p[2], 0.f);
    } else if (t < NROWS + DIM * DIM) {
        int i = t - NROWS;
        int n = i >> 7, k = i & 127;
        Wt[i] = __float2bfloat16(W[k * DIM + n]);  // Wt[n][k] = W[k][n]
    }
}

// ---------- xW = x @ W via bf16 MFMA, output bf16 ----------
// One wave per 16x16 output tile; K=128 -> 4 mfma_f32_16x16x32_bf16.
// A frag: lane m = lane&15, k = (lane>>4)*8 + i (8 contiguous k, row-major x).
// B frag: lane n = lane&15, same k grouping (8 contiguous k of Wt row n).
// D: col = lane&15, row = (lane>>4)*4 + reg   [measured: learn_hip m89]
__global__ __launch_bounds__(256) void xw_mfma(const float* __restrict__ x,
                                               const __hip_bfloat16* __restrict__ Wt,
                                               __hip_bfloat16* __restrict__ xWb) {
    int wave = threadIdx.x >> 6;
    int lane = threadIdx.x & 63;
    int tile = blockIdx.x * 4 + wave;          // 0..4095
    int m0 = (tile >> 3) << 4;
    int n0 = (tile & 7) << 4;
    int r = lane & 15;
    int kg = lane >> 4;                        // 0..3
    const float* xr = x + (size_t)(m0 + r) * DIM + kg * 8;
    const __hip_bfloat16* br = Wt + (size_t)(n0 + r) * DIM + kg * 8;
    f32x4 acc = {0.f, 0.f, 0.f, 0.f};
#pragma unroll
    for (int kb = 0; kb < 4; ++kb) {
        float4 a0 = *(const float4*)(xr + kb * 32);
        float4 a1 = *(const float4*)(xr + kb * 32 + 4);
        bf16x8 af;
        union { __hip_bfloat16 h; short s; } u;
        u.h = __float2bfloat16(a0.x); af[0] = u.s;
        u.h = __float2bfloat16(a0.y); af[1] = u.s;
        u.h = __float2bfloat16(a0.z); af[2] = u.s;
        u.h = __float2bfloat16(a0.w); af[3] = u.s;
        u.h = __float2bfloat16(a1.x); af[4] = u.s;
        u.h = __float2bfloat16(a1.y); af[5] = u.s;
        u.h = __float2bfloat16(a1.z); af[6] = u.s;
        u.h = __float2bfloat16(a1.w); af[7] = u.s;
        bf16x8 bfr = *(const bf16x8*)(br + kb * 32);
        acc = __builtin_amdgcn_mfma_f32_16x16x32_bf16(af, bfr, acc, 0, 0, 0);
    }
    int col = n0 + r;
    int rbase = m0 + (kg << 2);
#pragma unroll
    for (int reg = 0; reg < 4; ++reg)
        xWb[(size_t)(rbase + reg) * DIM + col] = __float2bfloat16(acc[reg]);
}

// ---------- branchless sorted top-4 insert (ascending, ids) ----------
__device__ __forceinline__ void ins(float& v0, float& v1, float& v2, float& v3,
                                    int& i0, int& i1, int& i2, int& i3,
                                    float s, int j) {
    bool c3 = s < v3, c2 = s < v2, c1 = s < v1, c0 = s < v0;
    float nv3 = c3 ? (c2 ? v2 : s) : v3;  int n3 = c3 ? (c2 ? i2 : j) : i3;
    float nv2 = c2 ? (c1 ? v1 : s) : v2;  int n2 = c2 ? (c1 ? i1 : j) : i2;
    float nv1 = c1 ? (c0 ? v0 : s) : v1;  int n1 = c1 ? (c0 ? i0 : j) : i1;
    float nv0 = c0 ? s : v0;              int n0 = c0 ? j : i0;
    v3 = nv3; v2 = nv2; v1 = nv1; v0 = nv0;
    i3 = n3;  i2 = n2;  i1 = n1;  i0 = n0;
}

// ---------- top-4 scan + butterfly merge + gather epilogue ----------
__global__ __launch_bounds__(256) void topk_agg(const float4* __restrict__ pos4,
                                                const __hip_bfloat16* __restrict__ xWb,
                                                const float* __restrict__ bias,
                                                float* __restrict__ out) {
    int lane = threadIdx.x & 63;
    int wave = threadIdx.x >> 6;
    int rowbase = blockIdx.x * (4 * RPW) + wave * RPW;   // 8 rows/block
    int batch = rowbase >> 12;
    int ibase = rowbase & (NPTS - 1);
    const float4* pb = pos4 + (size_t)batch * NPTS;

    float cx[RPW], cy[RPW], cz[RPW];
    float v0[RPW], v1[RPW], v2[RPW], v3[RPW];
    int   i0[RPW], i1[RPW], i2[RPW], i3[RPW];
#pragma unroll
    for (int k = 0; k < RPW; ++k) {
        float4 c = pb[ibase + k];
        cx[k] = c.x; cy[k] = c.y; cz[k] = c.z;
        v0[k] = v1[k] = v2[k] = v3[k] = 3.4e38f;
        i0[k] = i1[k] = i2[k] = i3[k] = 0;
    }

#pragma unroll 2
    for (int j = lane; j < NPTS; j += 64) {
        float4 p = pb[j];
#pragma unroll
        for (int k = 0; k < RPW; ++k) {
            float dx = cx[k] - p.x, dy = cy[k] - p.y, dz = cz[k] - p.z;
            float d2 = fmaf(dx, dx, fmaf(dy, dy, dz * dz));
            ins(v0[k], v1[k], v2[k], v3[k], i0[k], i1[k], i2[k], i3[k], d2, j);
        }
    }

    // butterfly: after 6 xor steps every lane holds the global top-4
#pragma unroll
    for (int k = 0; k < RPW; ++k) {
        for (int off = 1; off < 64; off <<= 1) {
            float p0 = __shfl_xor(v0[k], off), p1 = __shfl_xor(v1[k], off);
            float p2 = __shfl_xor(v2[k], off), p3 = __shfl_xor(v3[k], off);
            int   q0 = __shfl_xor(i0[k], off), q1 = __shfl_xor(i1[k], off);
            int   q2 = __shfl_xor(i2[k], off), q3 = __shfl_xor(i3[k], off);
            ins(v0[k], v1[k], v2[k], v3[k], i0[k], i1[k], i2[k], i3[k], p0, q0);
            ins(v0[k], v1[k], v2[k], v3[k], i0[k], i1[k], i2[k], i3[k], p1, q1);
            ins(v0[k], v1[k], v2[k], v3[k], i0[k], i1[k], i2[k], i3[k], p2, q2);
            ins(v0[k], v1[k], v2[k], v3[k], i0[k], i1[k], i2[k], i3[k], p3, q3);
        }
    }

    // epilogue: lane owns channels (2*lane, 2*lane+1)
    int c = lane << 1;
    float2 bb = *(const float2*)(bias + c);
    const unsigned short* xu = (const unsigned short*)xWb;
    size_t bbase = ((size_t)batch * NPTS) << 7;
#pragma unroll
    for (int k = 0; k < RPW; ++k) {
        float w0 = __expf(-(v0[k] + 1e-8f) * 0.5f);
        float w1 = __expf(-(v1[k] + 1e-8f) * 0.5f);
        float w2 = __expf(-(v2[k] + 1e-8f) * 0.5f);
        float w3 = __expf(-(v3[k] + 1e-8f) * 0.5f);
        float inv = 1.0f / (w0 + w1 + w2 + w3 + 1e-8f);
        w0 *= inv; w1 *= inv; w2 *= inv; w3 *= inv;
        ushort2 a0 = *(const ushort2*)(xu + bbase + ((size_t)i0[k] << 7) + c);
        ushort2 a1 = *(const ushort2*)(xu + bbase + ((size_t)i1[k] << 7) + c);
        ushort2 a2 = *(const ushort2*)(xu + bbase + ((size_t)i2[k] << 7) + c);
        ushort2 a3 = *(const ushort2*)(xu + bbase + ((size_t)i3[k] << 7) + c);
        float ox = bb.x + w0 * __uint_as_float((unsigned)a0.x << 16)
                        + w1 * __uint_as_float((unsigned)a1.x << 16)
                        + w2 * __uint_as_float((unsigned)a2.x << 16)
                        + w3 * __uint_as_float((unsigned)a3.x << 16);
        float oy = bb.y + w0 * __uint_as_float((unsigned)a0.y << 16)
                        + w1 * __uint_as_float((unsigned)a1.y << 16)
                        + w2 * __uint_as_float((unsigned)a2.y << 16)
                        + w3 * __uint_as_float((unsigned)a3.y << 16);
        *(float2*)(out + (((size_t)(rowbase + k)) << 7) + c) = make_float2(ox, oy);
    }
}

extern "C" void kernel_launch(void* const* d_in, const int* in_sizes, int n_in,
                              void* d_out, int out_size, void* d_ws, size_t ws_size,
                              hipStream_t stream) {
    const float* x    = (const float*)d_in[0];  // [2,4096,128]
    const float* pos  = (const float*)d_in[1];  // [2,4096,3]
    const float* W    = (const float*)d_in[2];  // [128,128]
    const float* bias = (const float*)d_in[3];  // [128]
    float* out = (float*)d_out;                 // [2,4096,128] f32

    // workspace layout (2.16 MB < 4 MB proven available)
    char* ws = (char*)d_ws;
    __hip_bfloat16* xWb = (__hip_bfloat16*)ws;                       // 2 MB
    float4* pos4 = (float4*)(ws + (size_t)NROWS * DIM * 2);          // 128 KB
    __hip_bfloat16* Wt = (__hip_bfloat16*)(ws + (size_t)NROWS * DIM * 2
                                              + (size_t)NROWS * 16); // 32 KB

    prep<<<(NROWS + DIM * DIM + 255) / 256, 256, 0, stream>>>(pos, W, pos4, Wt);
    xw_mfma<<<(NROWS / 16) * (DIM / 16) / 4, 256, 0, stream>>>(x, Wt, xWb);
    topk_agg<<<NROWS / (4 * RPW), 256, 0, stream>>>(pos4, xWb, bias, out);
}

// Round 4
// 91.355 us; speedup vs baseline: 1.4663x; 1.1433x over previous
//
#include <hip/hip_runtime.h>
#include <hip/hip_bf16.h>

#define NPTS 4096
#define NROWS 8192   // B*N
#define DIM 128

typedef __attribute__((ext_vector_type(8))) short bf16x8;
typedef __attribute__((ext_vector_type(4))) float f32x4;

// ---------- prep: pos -> float4[8192], W -> W^T bf16 ----------
__global__ __launch_bounds__(256) void prep(const float* __restrict__ pos,
                                            const float* __restrict__ W,
                                            float4* __restrict__ pos4,
                                            __hip_bfloat16* __restrict__ Wt) {
    int t = blockIdx.x * 256 + threadIdx.x;
    if (t < NROWS) {
        const float* p = pos + (size_t)t * 3;
        pos4[t] = make_float4(p[0], p[1], p[2], 0.f);
    } else if (t < NROWS + DIM * DIM) {
        int i = t - NROWS;
        int n = i >> 7, k = i & 127;
        Wt[i] = __float2bfloat16(W[k * DIM + n]);  // Wt[n][k] = W[k][n]
    }
}

// ---------- xW = x @ W via bf16 MFMA, output bf16 (round-2, verified) ----------
__global__ __launch_bounds__(256) void xw_mfma(const float* __restrict__ x,
                                               const __hip_bfloat16* __restrict__ Wt,
                                               __hip_bfloat16* __restrict__ xWb) {
    int wave = threadIdx.x >> 6;
    int lane = threadIdx.x & 63;
    int tile = blockIdx.x * 4 + wave;          // 0..4095
    int m0 = (tile >> 3) << 4;
    int n0 = (tile & 7) << 4;
    int r = lane & 15;
    int kg = lane >> 4;                        // 0..3
    const float* xr = x + (size_t)(m0 + r) * DIM + kg * 8;
    const __hip_bfloat16* br = Wt + (size_t)(n0 + r) * DIM + kg * 8;
    f32x4 acc = {0.f, 0.f, 0.f, 0.f};
#pragma unroll
    for (int kb = 0; kb < 4; ++kb) {
        float4 a0 = *(const float4*)(xr + kb * 32);
        float4 a1 = *(const float4*)(xr + kb * 32 + 4);
        bf16x8 af;
        union { __hip_bfloat16 h; short s; } u;
        u.h = __float2bfloat16(a0.x); af[0] = u.s;
        u.h = __float2bfloat16(a0.y); af[1] = u.s;
        u.h = __float2bfloat16(a0.z); af[2] = u.s;
        u.h = __float2bfloat16(a0.w); af[3] = u.s;
        u.h = __float2bfloat16(a1.x); af[4] = u.s;
        u.h = __float2bfloat16(a1.y); af[5] = u.s;
        u.h = __float2bfloat16(a1.z); af[6] = u.s;
        u.h = __float2bfloat16(a1.w); af[7] = u.s;
        bf16x8 bfr = *(const bf16x8*)(br + kb * 32);
        acc = __builtin_amdgcn_mfma_f32_16x16x32_bf16(af, bfr, acc, 0, 0, 0);
    }
    int col = n0 + r;
    int rbase = m0 + (kg << 2);
#pragma unroll
    for (int reg = 0; reg < 4; ++reg)
        xWb[(size_t)(rbase + reg) * DIM + col] = __float2bfloat16(acc[reg]);
}

// ---------- exact f64 packed key: key = f64(d2) with low 12 bits = j ----------
// v_cvt_f64_f32 is lossless (29 trailing zero mantissa bits); OR-ing j only
// breaks ties on bit-identical d2, where it picks lowest index = jax top_k.
__device__ __forceinline__ double mkkey(float d2, int j) {
    return __longlong_as_double(__double_as_longlong((double)d2) |
                                (unsigned long long)(unsigned)j);
}

// sorted-ascending insert: 7 v_min/max_f64
__device__ __forceinline__ void kins(double& k0, double& k1, double& k2,
                                     double& k3, double s) {
    double c = fmax(k0, s); k0 = fmin(k0, s);
    double t = fmax(k1, c); k1 = fmin(k1, c); c = t;
    t = fmax(k2, c);        k2 = fmin(k2, c); c = t;
    k3 = fmin(k3, c);
}

// merge two sorted-asc 4-lists -> 4 smallest sorted: 12 v_min/max_f64
__device__ __forceinline__ void kmerge(double& a0, double& a1, double& a2,
                                       double& a3, double b0, double b1,
                                       double b2, double b3) {
    double m0 = fmin(a0, b3), m1 = fmin(a1, b2);
    double m2 = fmin(a2, b1), m3 = fmin(a3, b0);
    double t0 = fmin(m0, m2), t2 = fmax(m0, m2);
    double t1 = fmin(m1, m3), t3 = fmax(m1, m3);
    a0 = fmin(t0, t1); a1 = fmax(t0, t1);
    a2 = fmin(t2, t3); a3 = fmax(t2, t3);
}

// 4 waves/block: wave = group*2 + half. Each wave scans NPTS/2 candidates
// for 2 rows; cross-half merge via LDS; half-0 wave does the epilogue.
__global__ __launch_bounds__(256) void topk_agg(const float4* __restrict__ pos4,
                                                const __hip_bfloat16* __restrict__ xWb,
                                                const float* __restrict__ bias,
                                                float* __restrict__ out) {
    int lane = threadIdx.x & 63;
    int wave = threadIdx.x >> 6;
    int group = wave >> 1;
    int half = wave & 1;
    int rowbase = blockIdx.x * 4 + group * 2;   // 4 rows/block
    int batch = rowbase >> 12;
    int ibase = rowbase & (NPTS - 1);
    const float4* pb = pos4 + (size_t)batch * NPTS;

    float4 q0 = pb[ibase], q1 = pb[ibase + 1];
    const double INF = __builtin_inf();
    double a0 = INF, a1 = INF, a2 = INF, a3 = INF;   // row 0 keys
    double b0 = INF, b1 = INF, b2 = INF, b3 = INF;   // row 1 keys

    int jbase = (half << 11) + lane;
#pragma unroll 4
    for (int t = 0; t < 32; ++t) {
        int j = jbase + (t << 6);
        float4 p = pb[j];
        float dx = q0.x - p.x, dy = q0.y - p.y, dz = q0.z - p.z;
        float d2 = fmaf(dx, dx, fmaf(dy, dy, dz * dz));
        kins(a0, a1, a2, a3, mkkey(d2, j));
        dx = q1.x - p.x; dy = q1.y - p.y; dz = q1.z - p.z;
        d2 = fmaf(dx, dx, fmaf(dy, dy, dz * dz));
        kins(b0, b1, b2, b3, mkkey(d2, j));
    }

    // intra-wave butterfly: 6 xor steps, bitonic merge each
#pragma unroll
    for (int off = 1; off < 64; off <<= 1) {
        double p0 = __shfl_xor(a0, off), p1 = __shfl_xor(a1, off);
        double p2 = __shfl_xor(a2, off), p3 = __shfl_xor(a3, off);
        kmerge(a0, a1, a2, a3, p0, p1, p2, p3);
        p0 = __shfl_xor(b0, off); p1 = __shfl_xor(b1, off);
        p2 = __shfl_xor(b2, off); p3 = __shfl_xor(b3, off);
        kmerge(b0, b1, b2, b3, p0, p1, p2, p3);
    }

    // cross-half exchange via LDS
    __shared__ double lds[2][2][2][4];   // [group][half][row][slot]
    if (lane == 0) {
        lds[group][half][0][0] = a0; lds[group][half][0][1] = a1;
        lds[group][half][0][2] = a2; lds[group][half][0][3] = a3;
        lds[group][half][1][0] = b0; lds[group][half][1][1] = b1;
        lds[group][half][1][2] = b2; lds[group][half][1][3] = b3;
    }
    __syncthreads();
    if (half) return;

    kmerge(a0, a1, a2, a3, lds[group][1][0][0], lds[group][1][0][1],
                           lds[group][1][0][2], lds[group][1][0][3]);
    kmerge(b0, b1, b2, b3, lds[group][1][1][0], lds[group][1][1][1],
                           lds[group][1][1][2], lds[group][1][1][3]);

    // epilogue: lane owns channels (2*lane, 2*lane+1)
    int c = lane << 1;
    float2 bb = *(const float2*)(bias + c);
    const unsigned short* xu = (const unsigned short*)xWb;
    size_t bbase = ((size_t)batch * NPTS) << 7;
#pragma unroll
    for (int k = 0; k < 2; ++k) {
        double k0 = k ? b0 : a0, k1 = k ? b1 : a1;
        double k2 = k ? b2 : a2, k3 = k ? b3 : a3;
        unsigned i0 = (unsigned)__double_as_longlong(k0) & 0xFFFu;
        unsigned i1 = (unsigned)__double_as_longlong(k1) & 0xFFFu;
        unsigned i2 = (unsigned)__double_as_longlong(k2) & 0xFFFu;
        unsigned i3 = (unsigned)__double_as_longlong(k3) & 0xFFFu;
        float d0 = (float)k0, d1 = (float)k1, d2 = (float)k2, d3 = (float)k3;
        float w0 = __expf(-(d0 + 1e-8f) * 0.5f);
        float w1 = __expf(-(d1 + 1e-8f) * 0.5f);
        float w2 = __expf(-(d2 + 1e-8f) * 0.5f);
        float w3 = __expf(-(d3 + 1e-8f) * 0.5f);
        float inv = 1.0f / (w0 + w1 + w2 + w3 + 1e-8f);
        w0 *= inv; w1 *= inv; w2 *= inv; w3 *= inv;
        ushort2 g0 = *(const ushort2*)(xu + bbase + ((size_t)i0 << 7) + c);
        ushort2 g1 = *(const ushort2*)(xu + bbase + ((size_t)i1 << 7) + c);
        ushort2 g2 = *(const ushort2*)(xu + bbase + ((size_t)i2 << 7) + c);
        ushort2 g3 = *(const ushort2*)(xu + bbase + ((size_t)i3 << 7) + c);
        float ox = bb.x + w0 * __uint_as_float((unsigned)g0.x << 16)
                        + w1 * __uint_as_float((unsigned)g1.x << 16)
                        + w2 * __uint_as_float((unsigned)g2.x << 16)
                        + w3 * __uint_as_float((unsigned)g3.x << 16);
        float oy = bb.y + w0 * __uint_as_float((unsigned)g0.y << 16)
                        + w1 * __uint_as_float((unsigned)g1.y << 16)
                        + w2 * __uint_as_float((unsigned)g2.y << 16)
                        + w3 * __uint_as_float((unsigned)g3.y << 16);
        *(float2*)(out + (((size_t)(rowbase + k)) << 7) + c) = make_float2(ox, oy);
    }
}

extern "C" void kernel_launch(void* const* d_in, const int* in_sizes, int n_in,
                              void* d_out, int out_size, void* d_ws, size_t ws_size,
                              hipStream_t stream) {
    const float* x    = (const float*)d_in[0];  // [2,4096,128]
    const float* pos  = (const float*)d_in[1];  // [2,4096,3]
    const float* W    = (const float*)d_in[2];  // [128,128]
    const float* bias = (const float*)d_in[3];  // [128]
    float* out = (float*)d_out;                 // [2,4096,128] f32

    char* ws = (char*)d_ws;
    __hip_bfloat16* xWb = (__hip_bfloat16*)ws;                       // 2 MB
    float4* pos4 = (float4*)(ws + (size_t)NROWS * DIM * 2);          // 128 KB
    __hip_bfloat16* Wt = (__hip_bfloat16*)(ws + (size_t)NROWS * DIM * 2
                                              + (size_t)NROWS * 16); // 32 KB

    prep<<<(NROWS + DIM * DIM + 255) / 256, 256, 0, stream>>>(pos, W, pos4, Wt);
    xw_mfma<<<(NROWS / 16) * (DIM / 16) / 4, 256, 0, stream>>>(x, Wt, xWb);
    topk_agg<<<NROWS / 4, 256, 0, stream>>>(pos4, xWb, bias, out);
}